// Round 2
// baseline (450.689 us; speedup 1.0000x reference)
//
#include <hip/hip_runtime.h>

#define N_NODES 100000
#define N_EDGES 640000
#define D       128        // D_IN == D_OUT
#define NPW     8          // nodes per wave in gemv
#define WAVES   4
#define NPB     (NPW*WAVES)           // 32
#define GROUPS  (N_NODES/NPB)         // 3125

static_assert(N_NODES % NPB == 0, "exact node tiling");

#define SCAN_CHUNK  1024
#define SCAN_BLOCKS ((N_NODES + SCAN_CHUNK - 1) / SCAN_CHUNK)   // 98

// ---- d_ws layout (int32 words) -------------------------------------------
// cnt    [0      , 100000)   per-dst edge count (histogram; gemv reads it)
// offs   [100000 , 200000)   CSR row starts (exclusive scan of cnt)
// cursor [200000 , 300000)   scatter cursors (init = offs, consumed)
// col    [300000 , 940000)   CSR column indices = src node ids
// bsum   [940000 , 940128)   per-chunk sums for the two-level scan
// total ~3.76 MB
#define WS_CNT    0
#define WS_OFFS   100000
#define WS_CURSOR 200000
#define WS_COL    300000
#define WS_BSUM   940000

// ---------------------------------------------------------------------------
// 1) histogram: cnt[dst]++
// ---------------------------------------------------------------------------
__global__ __launch_bounds__(256) void k_hist(const int* __restrict__ ei, int* cnt)
{
    int e = blockIdx.x * 256 + threadIdx.x;          // grid sized exactly
    atomicAdd(&cnt[ei[N_EDGES + e]], 1);
}

// ---------------------------------------------------------------------------
// 2a) per-chunk exclusive scan (Hillis-Steele in LDS) + chunk totals
// ---------------------------------------------------------------------------
__global__ __launch_bounds__(SCAN_CHUNK) void k_scan_a(
    const int* __restrict__ cnt, int* offs, int* bsum)
{
    __shared__ int s[SCAN_CHUNK];
    int t = threadIdx.x, b = blockIdx.x;
    int i = b * SCAN_CHUNK + t;
    int v = (i < N_NODES) ? cnt[i] : 0;
    s[t] = v;
    __syncthreads();
    for (int off = 1; off < SCAN_CHUNK; off <<= 1) {
        int u = s[t];
        int w = (t >= off) ? s[t - off] : 0;
        __syncthreads();
        s[t] = u + w;
        __syncthreads();
    }
    if (i < N_NODES) offs[i] = s[t] - v;             // exclusive within chunk
    if (t == SCAN_CHUNK - 1) bsum[b] = s[t];         // chunk total
}

// ---------------------------------------------------------------------------
// 2b) exclusive scan of the 98 chunk totals (tiny, serial in LDS)
// ---------------------------------------------------------------------------
__global__ __launch_bounds__(128) void k_scan_b(int* bsum)
{
    __shared__ int s[128];
    int t = threadIdx.x;
    if (t < SCAN_BLOCKS) s[t] = bsum[t];
    __syncthreads();
    if (t == 0) {
        int run = 0;
        for (int j = 0; j < SCAN_BLOCKS; ++j) { int tmp = s[j]; s[j] = run; run += tmp; }
    }
    __syncthreads();
    if (t < SCAN_BLOCKS) bsum[t] = s[t];
}

// ---------------------------------------------------------------------------
// 2c) add chunk offsets; init cursor = offs
// ---------------------------------------------------------------------------
__global__ __launch_bounds__(SCAN_CHUNK) void k_scan_c(
    int* offs, int* cursor, const int* __restrict__ bsum)
{
    int i = blockIdx.x * SCAN_CHUNK + threadIdx.x;
    if (i < N_NODES) {
        int o = offs[i] + bsum[blockIdx.x];
        offs[i] = o;
        cursor[i] = o;
    }
}

// ---------------------------------------------------------------------------
// 3) bucket edges: col[pos] = src, grouped by dst
// ---------------------------------------------------------------------------
__global__ __launch_bounds__(256) void k_scatter(
    const int* __restrict__ ei, int* cursor, int* col)
{
    int e = blockIdx.x * 256 + threadIdx.x;
    int src = ei[e];
    int dst = ei[N_EDGES + e];
    int pos = atomicAdd(&cursor[dst], 1);
    col[pos] = src;
}

// ---------------------------------------------------------------------------
// 4) gather: nsum[n] = sum over neighbors of x[src]   (one wave per node)
//    nsum lives in d_out; every row fully written -> no memset of d_out.
// ---------------------------------------------------------------------------
__global__ __launch_bounds__(256) void k_gather(
    const float* __restrict__ x, const int* __restrict__ offs,
    const int* __restrict__ cnt, const int* __restrict__ col,
    float* nsum)
{
    int wave = threadIdx.x >> 6, lane = threadIdx.x & 63;
    int node = blockIdx.x * 4 + wave;                // grid = N_NODES/4 exact
    int start = offs[node];
    int deg   = cnt[node];

    float2 acc = make_float2(0.f, 0.f);
    int j = 0;
    for (; j + 2 <= deg; j += 2) {                   // 2 rows in flight
        int s0 = col[start + j];
        int s1 = col[start + j + 1];
        float2 a = ((const float2*)(x + (size_t)s0 * D))[lane];
        float2 b = ((const float2*)(x + (size_t)s1 * D))[lane];
        acc.x += a.x + b.x;
        acc.y += a.y + b.y;
    }
    if (j < deg) {
        int s0 = col[start + j];
        float2 a = ((const float2*)(x + (size_t)s0 * D))[lane];
        acc.x += a.x;
        acc.y += a.y;
    }
    ((float2*)(nsum + (size_t)node * D))[lane] = acc;
}

// ---------------------------------------------------------------------------
// 5) fused GEMV: out[n] = x[n]@W_self + (nsum[n]*inv)@W_neigh + b_self+b_neigh
//    - combined 256x128 W in LDS (128 KB), staged once per block
//    - A values are wave-uniform: uniform-address float4 global loads
//      (HW broadcast, no LDS round-trip)
//    - inv folded out of the k-loop via separate accS/accN accumulators
//    - in place on d_out: each row read (sum) then written by its own wave
// ---------------------------------------------------------------------------
extern __shared__ float Wc[];   // [256][128]

__global__ __launch_bounds__(256) void k_gemv(
    const float* __restrict__ x,
    const float* __restrict__ Wself,  const float* __restrict__ bself,
    const float* __restrict__ Wneigh, const float* __restrict__ bneigh,
    const int* __restrict__ cnt,
    float* out /* = nsum on entry */)
{
    int t = threadIdx.x;

    {   // stage W: rows 0..127 = W_self, rows 128..255 = W_neigh
        const float4* ws4 = (const float4*)Wself;
        const float4* wn4 = (const float4*)Wneigh;
        float4* wc4 = (float4*)Wc;
        #pragma unroll
        for (int i = 0; i < 16; ++i) {               // 4096 float4 per half
            int idx = i * 256 + t;
            wc4[idx]        = ws4[idx];
            wc4[idx + 4096] = wn4[idx];
        }
    }
    __syncthreads();

    int wave = t >> 6, lane = t & 63;

    float2 bias;
    {
        float2 bs = ((const float2*)bself)[lane];
        float2 bn = ((const float2*)bneigh)[lane];
        bias.x = bs.x + bn.x;
        bias.y = bs.y + bn.y;
    }

    for (int g = blockIdx.x; g < GROUPS; g += gridDim.x) {
        int base = g * NPB + wave * NPW;

        float2 accS[NPW], accN[NPW];
        #pragma unroll
        for (int n = 0; n < NPW; ++n) {
            accS[n] = make_float2(0.f, 0.f);
            accN[n] = make_float2(0.f, 0.f);
        }

        // ---- x @ W_self (W rows 0..127) ----
        {
            const float4* ap[NPW];
            #pragma unroll
            for (int n = 0; n < NPW; ++n)
                ap[n] = (const float4*)(x + (size_t)(base + n) * D);
            for (int kc = 0; kc < 32; ++kc) {        // 4 k per iter
                int k = kc * 4;
                float2 w0 = ((const float2*)(Wc + (size_t)(k + 0) * D))[lane];
                float2 w1 = ((const float2*)(Wc + (size_t)(k + 1) * D))[lane];
                float2 w2 = ((const float2*)(Wc + (size_t)(k + 2) * D))[lane];
                float2 w3 = ((const float2*)(Wc + (size_t)(k + 3) * D))[lane];
                #pragma unroll
                for (int n = 0; n < NPW; ++n) {
                    float4 a = ap[n][kc];            // wave-uniform -> broadcast
                    accS[n].x = fmaf(a.x, w0.x, accS[n].x);
                    accS[n].y = fmaf(a.x, w0.y, accS[n].y);
                    accS[n].x = fmaf(a.y, w1.x, accS[n].x);
                    accS[n].y = fmaf(a.y, w1.y, accS[n].y);
                    accS[n].x = fmaf(a.z, w2.x, accS[n].x);
                    accS[n].y = fmaf(a.z, w2.y, accS[n].y);
                    accS[n].x = fmaf(a.w, w3.x, accS[n].x);
                    accS[n].y = fmaf(a.w, w3.y, accS[n].y);
                }
            }
        }

        // ---- nsum @ W_neigh (W rows 128..255) ----
        {
            const float4* ap[NPW];
            #pragma unroll
            for (int n = 0; n < NPW; ++n)
                ap[n] = (const float4*)(out + (size_t)(base + n) * D);
            for (int kc = 0; kc < 32; ++kc) {
                int k = 128 + kc * 4;
                float2 w0 = ((const float2*)(Wc + (size_t)(k + 0) * D))[lane];
                float2 w1 = ((const float2*)(Wc + (size_t)(k + 1) * D))[lane];
                float2 w2 = ((const float2*)(Wc + (size_t)(k + 2) * D))[lane];
                float2 w3 = ((const float2*)(Wc + (size_t)(k + 3) * D))[lane];
                #pragma unroll
                for (int n = 0; n < NPW; ++n) {
                    float4 a = ap[n][kc];
                    accN[n].x = fmaf(a.x, w0.x, accN[n].x);
                    accN[n].y = fmaf(a.x, w0.y, accN[n].y);
                    accN[n].x = fmaf(a.y, w1.x, accN[n].x);
                    accN[n].y = fmaf(a.y, w1.y, accN[n].y);
                    accN[n].x = fmaf(a.z, w2.x, accN[n].x);
                    accN[n].y = fmaf(a.z, w2.y, accN[n].y);
                    accN[n].x = fmaf(a.w, w3.x, accN[n].x);
                    accN[n].y = fmaf(a.w, w3.y, accN[n].y);
                }
            }
        }

        #pragma unroll
        for (int n = 0; n < NPW; ++n) {
            int node = base + n;
            float inv = 1.0f / fmaxf((float)cnt[node], 1.0f);
            float2 o;
            o.x = fmaf(inv, accN[n].x, accS[n].x) + bias.x;
            o.y = fmaf(inv, accN[n].y, accS[n].y) + bias.y;
            ((float2*)(out + (size_t)node * D))[lane] = o;
        }
    }
}

// ---------------------------------------------------------------------------
extern "C" void kernel_launch(void* const* d_in, const int* in_sizes, int n_in,
                              void* d_out, int out_size, void* d_ws, size_t ws_size,
                              hipStream_t stream) {
    const float* x      = (const float*)d_in[0];
    const int*   ei     = (const int*)  d_in[1];   // harness contract: int32
    const float* Wself  = (const float*)d_in[2];
    const float* bself  = (const float*)d_in[3];
    const float* Wneigh = (const float*)d_in[4];
    const float* bneigh = (const float*)d_in[5];

    float* out = (float*)d_out;
    int*   ws  = (int*)d_ws;
    int* cnt    = ws + WS_CNT;
    int* offs   = ws + WS_OFFS;
    int* cursor = ws + WS_CURSOR;
    int* col    = ws + WS_COL;
    int* bsum   = ws + WS_BSUM;

    hipMemsetAsync(cnt, 0, N_NODES * sizeof(int), stream);

    k_hist   <<<N_EDGES / 256, 256, 0, stream>>>(ei, cnt);
    k_scan_a <<<SCAN_BLOCKS, SCAN_CHUNK, 0, stream>>>(cnt, offs, bsum);
    k_scan_b <<<1, 128, 0, stream>>>(bsum);
    k_scan_c <<<SCAN_BLOCKS, SCAN_CHUNK, 0, stream>>>(offs, cursor, bsum);
    k_scatter<<<N_EDGES / 256, 256, 0, stream>>>(ei, cursor, col);
    k_gather <<<N_NODES / 4, 256, 0, stream>>>(x, offs, cnt, col, out);

    size_t lds_bytes = 256 * 128 * sizeof(float);   // 128 KB
    hipFuncSetAttribute((const void*)k_gemv,
                        hipFuncAttributeMaxDynamicSharedMemorySize, (int)lds_bytes);
    k_gemv<<<256, 256, lds_bytes, stream>>>(x, Wself, bself, Wneigh, bneigh, cnt, out);
}

// Round 6
// 256.876 us; speedup vs baseline: 1.7545x; 1.7545x over previous
//
#include <hip/hip_runtime.h>

#define N_NODES 100000
#define N_EDGES 640000
#define D       128
#define NT      ((N_NODES + 127) / 128)    // 782 row-tiles for gemm

#define SCAN_CHUNK  1024
#define SCAN_BLOCKS ((N_NODES + SCAN_CHUNK - 1) / SCAN_CHUNK)   // 98

// ---- d_ws layout (4B words) ----------------------------------------------
#define WS_CNT    0          // int   [100000]
#define WS_OFFS   100000     // int   [100000]
#define WS_CURSOR 200000     // int   [100000]
#define WS_COL    300000     // int   [640000]
#define WS_BSUM   940000     // int   [1024]
#define WS_BIAS   941056     // f32   [128]
#define WS_WT     941184     // bf16  [32768] = 16384 words (pre-swizzled W^T)
// total ≈ 3.83 MB

// RNE float->bf16 (finite inputs only)
__device__ __forceinline__ unsigned short f2bf(float f) {
    union { float f; unsigned u; } c; c.f = f;
    unsigned r = c.u + 0x7fffu + ((c.u >> 16) & 1u);
    return (unsigned short)(r >> 16);
}

// ---------------------------------------------------------------------------
// prep: Wt_swz[n][k] (bf16, XOR-swizzled 16B units) + bias_sum
// Wt content: Wt[n][k] = Wcat[k][n], Wcat = [W_self ; W_neigh] (256 x 128).
// Global byte n*512 + (((k>>3) ^ (n&15))*16) + (k&7)*2 holds Wcat[k][n].
// GEMM copies this linearly to LDS and reads frags with the same XOR
// (rule #21: swizzle source + read, keep the LDS copy linear).
// ---------------------------------------------------------------------------
__global__ __launch_bounds__(256) void k_prepw(
    const float* __restrict__ Wself, const float* __restrict__ Wneigh,
    const float* __restrict__ bself, const float* __restrict__ bneigh,
    unsigned short* wt, float* bias)
{
    int i = blockIdx.x * 256 + threadIdx.x;       // grid 128 -> 32768 threads
    int k = i >> 7, n = i & 127;
    float v = (k < 128) ? Wself[k * 128 + n] : Wneigh[(k - 128) * 128 + n];
    int byte = n * 512 + (((k >> 3) ^ (n & 15)) << 4) + ((k & 7) << 1);
    *(unsigned short*)((char*)wt + byte) = f2bf(v);
    if (blockIdx.x == 0 && threadIdx.x < 128)
        bias[threadIdx.x] = bself[threadIdx.x] + bneigh[threadIdx.x];
}

// ---------------------------------------------------------------------------
// 1) histogram: cnt[dst]++
// ---------------------------------------------------------------------------
__global__ __launch_bounds__(256) void k_hist(const int* __restrict__ ei, int* cnt)
{
    int e = blockIdx.x * 256 + threadIdx.x;          // grid sized exactly
    atomicAdd(&cnt[ei[N_EDGES + e]], 1);
}

// ---------------------------------------------------------------------------
// 2) two-level exclusive scan of cnt -> offs
// ---------------------------------------------------------------------------
__global__ __launch_bounds__(SCAN_CHUNK) void k_scan_a(
    const int* __restrict__ cnt, int* offs, int* bsum)
{
    __shared__ int s[SCAN_CHUNK];
    int t = threadIdx.x, b = blockIdx.x;
    int i = b * SCAN_CHUNK + t;
    int v = (i < N_NODES) ? cnt[i] : 0;
    s[t] = v;
    __syncthreads();
    for (int off = 1; off < SCAN_CHUNK; off <<= 1) {
        int u = s[t];
        int w = (t >= off) ? s[t - off] : 0;
        __syncthreads();
        s[t] = u + w;
        __syncthreads();
    }
    if (i < N_NODES) offs[i] = s[t] - v;
    if (t == SCAN_CHUNK - 1) bsum[b] = s[t];
}

__global__ __launch_bounds__(128) void k_scan_b(int* bsum)
{
    __shared__ int s[128];
    int t = threadIdx.x;
    if (t < SCAN_BLOCKS) s[t] = bsum[t];
    __syncthreads();
    if (t == 0) {
        int run = 0;
        for (int j = 0; j < SCAN_BLOCKS; ++j) { int tmp = s[j]; s[j] = run; run += tmp; }
    }
    __syncthreads();
    if (t < SCAN_BLOCKS) bsum[t] = s[t];
}

__global__ __launch_bounds__(SCAN_CHUNK) void k_scan_c(
    int* offs, int* cursor, const int* __restrict__ bsum)
{
    int i = blockIdx.x * SCAN_CHUNK + threadIdx.x;
    if (i < N_NODES) {
        int o = offs[i] + bsum[blockIdx.x];
        offs[i] = o;
        cursor[i] = o;
    }
}

// ---------------------------------------------------------------------------
// 3) bucket edges: col[pos] = src, grouped by dst
// ---------------------------------------------------------------------------
__global__ __launch_bounds__(256) void k_scatter(
    const int* __restrict__ ei, int* cursor, int* col)
{
    int e = blockIdx.x * 256 + threadIdx.x;
    int src = ei[e];
    int dst = ei[N_EDGES + e];
    int pos = atomicAdd(&cursor[dst], 1);
    col[pos] = src;
}

// ---------------------------------------------------------------------------
// 4) gather MEAN (fp32) into d_out. One wave per node.
//    Parallel col prefetch (lane<deg) + __shfl broadcast -> no serial
//    dependent index loads; x-row loads pipeline 2-deep.
//    deg==0 -> acc 0, inv=1 -> mean 0 (matches reference clip(count,1)).
// ---------------------------------------------------------------------------
__global__ __launch_bounds__(256) void k_gather(
    const float* __restrict__ x, const int* __restrict__ offs,
    const int* __restrict__ cnt, const int* __restrict__ col,
    float* out)
{
    int node = blockIdx.x * 4 + (threadIdx.x >> 6);      // grid 25000 exact
    int l = threadIdx.x & 63;
    int start = offs[node];
    int deg   = cnt[node];

    float2 acc = make_float2(0.f, 0.f);
    for (int base = 0; base < deg; base += 64) {
        int idx = base + l;
        int c = (idx < deg) ? col[start + idx] : 0;
        int m = min(deg - base, 64);
        int j = 0;
        for (; j + 2 <= m; j += 2) {
            int s0 = __shfl(c, j);
            int s1 = __shfl(c, j + 1);
            float2 a = ((const float2*)(x + (size_t)s0 * D))[l];
            float2 b = ((const float2*)(x + (size_t)s1 * D))[l];
            acc.x += a.x + b.x;
            acc.y += a.y + b.y;
        }
        if (j < m) {
            int s0 = __shfl(c, j);
            float2 a = ((const float2*)(x + (size_t)s0 * D))[l];
            acc.x += a.x;
            acc.y += a.y;
        }
    }
    float inv = 1.0f / fmaxf((float)deg, 1.0f);
    float2 o = make_float2(acc.x * inv, acc.y * inv);
    ((float2*)(out + (size_t)node * D))[l] = o;
}

// ---------------------------------------------------------------------------
// 5) MFMA GEMM: out[r] = [x[r] | mean[r]] @ Wcat + bias   (bf16 in, fp32 acc)
//    - 128-row tile/block, 4 waves, each wave 32 rows x 128 cols
//    - A-tile LDS [128][256] bf16 (64KB), XOR-swizzled 16B units:
//        byte(r,k) = r*512 + (((k>>3) ^ (r&15))<<4) + (k&7)*2
//      staged from global fp32 (x + mean-in-d_out) via reg cvt + ds_write
//    - W LDS 64KB: linear copy of pre-swizzled Wt_swz global
//    - frag reads 2-way bank-aliased max (free, m136); acc[2][8] f32x4
//    - in place on d_out: global reads drain to regs before the barrier,
//      writes happen after the K-loop; blocks own disjoint rows (the tail
//      clamp targets the clamping block's own row range)
// ---------------------------------------------------------------------------
typedef __attribute__((ext_vector_type(8))) short bf16x8;
typedef __attribute__((ext_vector_type(4))) float f32x4;

extern __shared__ char ldsb[];

__global__ __launch_bounds__(256) void k_gemm(
    const float* __restrict__ x,
    const unsigned short* __restrict__ wt,
    const float* __restrict__ bias,
    float* outp)
{
    char* ldsA = ldsb;               // 65536 B
    char* ldsW = ldsb + 65536;       // 65536 B

    const int w = threadIdx.x >> 6, l = threadIdx.x & 63;
    const int r0 = blockIdx.x * 128;

    // ---- stage W: linear 16B copies (content already swizzled) ----
    {
        const uint4* wt4 = (const uint4*)wt;          // 4096 x 16B
        #pragma unroll
        for (int it = 0; it < 16; ++it) {
            int q = (w * 16 + it) * 64 + l;
            *(uint4*)(ldsW + (size_t)q * 16) = wt4[q];
        }
    }

    // ---- stage A: 32 rows per wave; halves: 0=x, 1=mean(d_out) ----
    {
        const float4* xf = (const float4*)x;
        const float4* mf = (const float4*)outp;
        float4 vx[16], vm[16];
        #pragma unroll
        for (int it = 0; it < 16; ++it) {
            int rl = 2 * it + (l >> 5);                       // 0..31
            int rg = min(r0 + w * 32 + rl, N_NODES - 1);      // clamp tail
            int j  = l & 31;
            vx[it] = xf[(size_t)rg * 32 + j];
            vm[it] = mf[(size_t)rg * 32 + j];
        }
        #pragma unroll
        for (int it = 0; it < 16; ++it) {
            int rl   = 2 * it + (l >> 5);
            int rloc = w * 32 + rl;
            int j    = l & 31;
            // x half: k = j*4..j*4+3 ; unit = j>>1, sub = (j&1)*8
            {
                int unit = ((j >> 1) ^ (rloc & 15));
                ushort4 b;
                b.x = f2bf(vx[it].x); b.y = f2bf(vx[it].y);
                b.z = f2bf(vx[it].z); b.w = f2bf(vx[it].w);
                *(ushort4*)(ldsA + rloc * 512 + (unit << 4) + ((j & 1) << 3)) = b;
            }
            // mean half: unit 16 + (j>>1); XOR with <=15 stays in [16,32)
            {
                int unit = ((16 + (j >> 1)) ^ (rloc & 15));
                ushort4 b;
                b.x = f2bf(vm[it].x); b.y = f2bf(vm[it].y);
                b.z = f2bf(vm[it].z); b.w = f2bf(vm[it].w);
                *(ushort4*)(ldsA + rloc * 512 + (unit << 4) + ((j & 1) << 3)) = b;
            }
        }
    }
    __syncthreads();

    const int ln = l & 15, kq = l >> 4;
    const int rA0 = w * 32 + ln;          // rg=0 local row; rA0&15 == ln
    const int rA1 = rA0 + 16;             // rg=1

    f32x4 acc[2][8];
    #pragma unroll
    for (int rg = 0; rg < 2; ++rg)
        #pragma unroll
        for (int cg = 0; cg < 8; ++cg)
            acc[rg][cg] = (f32x4){0.f, 0.f, 0.f, 0.f};

    #pragma unroll
    for (int ks = 0; ks < 8; ++ks) {
        int i = ks * 4 + kq;              // 16B-unit index 0..31
        bf16x8 a0 = *(const bf16x8*)(ldsA + rA0 * 512 + ((i ^ ln) << 4));
        bf16x8 a1 = *(const bf16x8*)(ldsA + rA1 * 512 + ((i ^ ln) << 4));
        #pragma unroll
        for (int cg = 0; cg < 8; ++cg) {
            int n = cg * 16 + ln;
            bf16x8 bfr = *(const bf16x8*)(ldsW + n * 512 + ((i ^ ln) << 4));
            acc[0][cg] = __builtin_amdgcn_mfma_f32_16x16x32_bf16(a0, bfr, acc[0][cg], 0, 0, 0);
            acc[1][cg] = __builtin_amdgcn_mfma_f32_16x16x32_bf16(a1, bfr, acc[1][cg], 0, 0, 0);
        }
    }

    // ---- epilogue: C/D layout col=ln, row=kq*4+q (m89-verified) ----
    float bv[8];
    #pragma unroll
    for (int cg = 0; cg < 8; ++cg) bv[cg] = bias[cg * 16 + ln];

    #pragma unroll
    for (int rg = 0; rg < 2; ++rg) {
        int rbase = r0 + w * 32 + rg * 16 + kq * 4;
        #pragma unroll
        for (int q = 0; q < 4; ++q) {
            int rr = rbase + q;
            if (rr < N_NODES) {
                float* op = outp + (size_t)rr * D + ln;
                #pragma unroll
                for (int cg = 0; cg < 8; ++cg)
                    op[cg * 16] = acc[rg][cg][q] + bv[cg];
            }
        }
    }
}

// ---------------------------------------------------------------------------
extern "C" void kernel_launch(void* const* d_in, const int* in_sizes, int n_in,
                              void* d_out, int out_size, void* d_ws, size_t ws_size,
                              hipStream_t stream) {
    const float* x      = (const float*)d_in[0];
    const int*   ei     = (const int*)  d_in[1];   // harness delivers int32
    const float* Wself  = (const float*)d_in[2];
    const float* bself  = (const float*)d_in[3];
    const float* Wneigh = (const float*)d_in[4];
    const float* bneigh = (const float*)d_in[5];

    float* out = (float*)d_out;
    int*   ws  = (int*)d_ws;
    int* cnt    = ws + WS_CNT;
    int* offs   = ws + WS_OFFS;
    int* cursor = ws + WS_CURSOR;
    int* col    = ws + WS_COL;
    int* bsum   = ws + WS_BSUM;
    float* bias = (float*)(ws + WS_BIAS);
    unsigned short* wt = (unsigned short*)(ws + WS_WT);

    hipMemsetAsync(cnt, 0, N_NODES * sizeof(int), stream);

    k_prepw  <<<128, 256, 0, stream>>>(Wself, Wneigh, bself, bneigh, wt, bias);
    k_hist   <<<N_EDGES / 256, 256, 0, stream>>>(ei, cnt);
    k_scan_a <<<SCAN_BLOCKS, SCAN_CHUNK, 0, stream>>>(cnt, offs, bsum);
    k_scan_b <<<1, 128, 0, stream>>>(bsum);
    k_scan_c <<<SCAN_BLOCKS, SCAN_CHUNK, 0, stream>>>(offs, cursor, bsum);
    k_scatter<<<N_EDGES / 256, 256, 0, stream>>>(ei, cursor, col);
    k_gather <<<N_NODES / 4, 256, 0, stream>>>(x, offs, cnt, col, out);

    size_t lds_bytes = 131072;
    hipFuncSetAttribute((const void*)k_gemm,
                        hipFuncAttributeMaxDynamicSharedMemorySize, (int)lds_bytes);
    k_gemm<<<NT, 256, lds_bytes, stream>>>(x, wt, bias, out);
}